// Round 8
// baseline (112.649 us; speedup 1.0000x reference)
//
#include <hip/hip_runtime.h>

// Problem constants (from reference setup_inputs)
constexpr int NPTS = 8192;   // points per batch
constexpr int NQ   = 2048;   // query points per batch
constexpr int NC   = 64;     // feature channels
constexpr int NS   = 32;     // nsample
constexpr int NCH  = 3 + 1 + NC;           // 68 output channels
constexpr int CS   = NQ * NS;              // channel stride in output (floats)

// Workspace layout (floats):  ftr : B*NPTS*NC  |  idx : B*NQ*NS (int32)

// R8: K1 = fused 256-thr [transpose | scan] kernel.
//  - transpose blocks: R2's 64x64 tile (16.6 KB LDS), coalesced both sides.
//  - scan blocks: R4-style global AoS prefetch-2 ballot scan, 4 queries/block,
//    NO barrier (waves retire independently -> tail queries absorbed by the
//    7 other resident blocks/CU), mbcnt prefix-popcount.
// Rationale (R5-R7 measurements): scan is tail/latency-bound, not
// VALU-bound (VALU floor ~2 us over 1024 SIMDs). R7's 1024-thr LDS-staged
// scan (2 blocks/CU + barrier) measured ~17 us vs R4's 256-thr global scan
// ~11 us. Occupancy + independent wave retirement beats LDS staging here.

union KLds {
    float tile[NC][65];      // transpose blocks (+1 pad: 2-way aliasing, free)
    int   idx[4][NS];        // scan blocks
};

__device__ __forceinline__ unsigned prefix_popc(unsigned long long m) {
    // popcount of m restricted to lanes below this one (v_mbcnt pair)
    return __builtin_amdgcn_mbcnt_hi((unsigned)(m >> 32),
           __builtin_amdgcn_mbcnt_lo((unsigned)m, 0u));
}

__global__ __launch_bounds__(256, 8) void scan_trans_kernel(
    const float* __restrict__ xyz,    // (B, NPTS, 3)
    const float* __restrict__ nxyz,   // (B, NQ, 3)
    const float* __restrict__ feat,   // (B, NC, NPTS)
    float* __restrict__ ftr,          // (B, NPTS, NC)
    int* __restrict__ gidx,           // (B, NQ, NS)
    float* __restrict__ out,          // (B, NCH, NQ, NS)
    int ntrans)
{
    __shared__ KLds u;
    const int bx = blockIdx.x;
    const int t  = threadIdx.x;

    if (bx < ntrans) {
        // ---- feature transpose: one 64-pt x 64-ch tile ----
        const int b  = bx >> 7;               // 128 t-blocks per batch
        const int tl = bx & 127;
        const int n0 = tl * 64;
        const float* fb = feat + (size_t)b * NC * NPTS;
        {
            const int pl = t & 63;
            const int c0 = t >> 6;            // 0..3
            #pragma unroll
            for (int i = 0; i < 16; ++i) {    // coalesced 256B rows
                const int c = c0 + 4 * i;
                u.tile[c][pl] = fb[(size_t)c * NPTS + n0 + pl];
            }
        }
        __syncthreads();
        float* tb = ftr + ((size_t)b * NPTS + n0) * NC;
        {
            const int cl = t & 63;
            const int pb = t >> 6;
            #pragma unroll
            for (int i = 0; i < 16; ++i) {    // coalesced 256B per point
                const int pp = pb + 4 * i;
                tb[(size_t)pp * NC + cl] = u.tile[cl][pp];  // (cl+pp)%32: 2-way, free
            }
        }
        return;
    }

    // ---- scan block: 4 queries (1 wave each), global AoS prefetch-2 ----
    const int sb   = bx - ntrans;
    const int qpb  = NQ / 4;                  // 512 scan-blocks per batch
    const int b    = sb / qpb;
    const int p0   = (sb - b * qpb) * 4;
    const int lane = t & 63;
    const int wave = t >> 6;                  // 0..3
    const int p    = p0 + wave;
    const float* xb = xyz + (size_t)b * NPTS * 3;
    int* idx_row = u.idx[wave];

    const float qx = nxyz[((size_t)b * NQ + p) * 3 + 0];
    const float qy = nxyz[((size_t)b * NQ + p) * 3 + 1];
    const float qz = nxyz[((size_t)b * NQ + p) * 3 + 2];

    int cnt = 0;      // wave-uniform hit count
    int first = -1;   // wave-uniform first-hit index

    // prefetch chunks 0,1 (AoS: 3 dwords per lane, 768B window per chunk)
    float x0 = xb[3 * lane + 0], y0 = xb[3 * lane + 1], z0 = xb[3 * lane + 2];
    float x1 = xb[3 * (64 + lane) + 0], y1 = xb[3 * (64 + lane) + 1],
          z1 = xb[3 * (64 + lane) + 2];

    for (int base = 0; base < NPTS; base += 64) {
        float xn = 0.f, yn = 0.f, zn = 0.f;
        const int pf = base + 128;
        if (pf < NPTS) {                      // wave-uniform guard
            xn = xb[3 * (pf + lane) + 0];
            yn = xb[3 * (pf + lane) + 1];
            zn = xb[3 * (pf + lane) + 2];
        }

        // strict per-op rounding, reference evaluation order (q<1.0 is
        // discontinuous -> no FMA contraction allowed)
        const float dx = __fsub_rn(qx, x0);
        const float dy = __fsub_rn(qy, y0);
        const float dz = __fsub_rn(qz, z0);
        const float t0 = __fmul_rn(__fmul_rn(dx, dx), 25.0f);
        const float t1 = __fmul_rn(__fmul_rn(dy, dy), 6.25f);
        const float t2 = __fmul_rn(__fmul_rn(dz, dz), 25.0f);
        const float qv = __fadd_rn(__fadd_rn(t0, t1), t2);
        const bool hit = qv < 1.0f;

        const unsigned long long m = __ballot(hit);
        if (first < 0 && m != 0ull)
            first = base + __builtin_ctzll(m);       // wave-uniform
        if (hit) {
            const int pos = cnt + (int)prefix_popc(m);
            if (pos < NS) idx_row[pos] = base + lane;
        }
        cnt += __popcll(m);
        if (cnt >= NS) break;                        // uniform early exit

        x0 = x1; y0 = y1; z0 = z1;
        x1 = xn; y1 = yn; z1 = zn;
    }
    if (cnt < NS) {
        const int f = (cnt == 0) ? 0 : first;        // pad (0 if empty)
        if (lane < NS && lane >= cnt) idx_row[lane] = f;
    }

    // epilogue: lanes 0..31 emit idx + channels 0..3
    if (lane < NS) {
        const int s = lane;
        const int j = idx_row[s];                    // same-wave LDS RAW: safe
        gidx[((size_t)b * NQ + p) * NS + s] = j;

        const float px = xb[3 * j + 0];
        const float py = xb[3 * j + 1];
        const float pz = xb[3 * j + 2];
        const float dx = __fsub_rn(px, qx);
        const float dy = __fsub_rn(py, qy);
        const float dz = __fsub_rn(pz, qz);
        const float d2 = __fadd_rn(__fadd_rn(__fmul_rn(dx, dx), __fmul_rn(dy, dy)),
                                   __fmul_rn(dz, dz));
        const float dist = __fsqrt_rn(d2);
        const float arg  = __fdiv_rn(-__fmul_rn(dist, dist), 0.02f);
        const float density = __fmul_rn(expf(arg), 4.0f);  // /0.25 == *4 exact
        const float gd = __fdiv_rn(1.0f, density);         // inf on underflow == ref

        float* ob = out + ((size_t)b * NCH * NQ + p) * NS + s;
        ob[0 * (size_t)CS] = px;
        ob[1 * (size_t)CS] = py;
        ob[2 * (size_t)CS] = pz;
        ob[3 * (size_t)CS] = gd;
    }
}

// ---------------------------------------------------------------------------
// K2: feature grouping (R4 version, measured at write-BW floor ~11-13 us).
// ---------------------------------------------------------------------------
__global__ __launch_bounds__(512, 8) void group_kernel(
    const int* __restrict__ gidx,     // (B, NQ, NS)
    const float* __restrict__ ftr,    // (B, NPTS, NC)
    float* __restrict__ out,          // (B, NCH, NQ, NS)
    int B)
{
    __shared__ float ldsc[NC][33];

    const int g = blockIdx.x;
    int b, p;
    if (B == 4) {
        b = (g & 7) >> 1;                     // XCD-pair -> batch
        p = ((g >> 3) << 1) | (g & 1);
    } else {
        b = g / NQ;
        p = g - b * NQ;
    }
    const int tid = threadIdx.x;

    // ---- gather phase: lane = (sl, cg) ----
    const int cg = tid & 15;                  // channel group 0..15 (float4)
    const int sl = tid >> 4;                  // sample 0..31
    const int j  = gidx[((size_t)b * NQ + p) * NS + sl];
    const float4 v = ((const float4*)(ftr + ((size_t)b * NPTS + j) * NC))[cg];
    ldsc[4 * cg + 0][sl] = v.x;               // bank (4cg+i+sl)%32 -> 2-way, free
    ldsc[4 * cg + 1][sl] = v.y;
    ldsc[4 * cg + 2][sl] = v.z;
    ldsc[4 * cg + 3][sl] = v.w;
    __syncthreads();

    // ---- store phase: lane = (c, s4) ----
    const int c  = tid >> 3;                  // channel 0..63
    const int s4 = (tid & 7) << 2;            // sample base 0,4,...,28
    float4 w;
    w.x = ldsc[c][s4 + 0];                    // bank (c+s4+i)%32 -> <=2-way, free
    w.y = ldsc[c][s4 + 1];
    w.z = ldsc[c][s4 + 2];
    w.w = ldsc[c][s4 + 3];
    float* op = out + (((size_t)b * NCH + 4 + c) * NQ + p) * NS + s4;
    *(float4*)op = w;                         // 8 x 128B segments per wave store
}

// ---------------------------------------------------------------------------
// Fallback (tiny ws): R1-style fused direct kernel.
// ---------------------------------------------------------------------------
__global__ __launch_bounds__(512, 8) void ellip_direct_kernel(
    const float* __restrict__ xyz,
    const float* __restrict__ nxyz,
    const float* __restrict__ feat,
    float* __restrict__ out)
{
    __shared__ int idx_s[8][NS];

    const int b    = blockIdx.y;
    const int p0   = blockIdx.x * 8;
    const int tid  = threadIdx.x;
    const int lane = tid & 63;
    const int wave = tid >> 6;
    const float* xb = xyz + (size_t)b * NPTS * 3;

    {
        const int p = p0 + wave;
        const float qx = nxyz[((size_t)b * NQ + p) * 3 + 0];
        const float qy = nxyz[((size_t)b * NQ + p) * 3 + 1];
        const float qz = nxyz[((size_t)b * NQ + p) * 3 + 2];
        int cnt = 0, first = -1;
        for (int base = 0; base < NPTS; base += 64) {
            const int i = base + lane;
            const float dx = __fsub_rn(qx, xb[i * 3 + 0]);
            const float dy = __fsub_rn(qy, xb[i * 3 + 1]);
            const float dz = __fsub_rn(qz, xb[i * 3 + 2]);
            const float t0 = __fmul_rn(__fmul_rn(dx, dx), 25.0f);
            const float t1 = __fmul_rn(__fmul_rn(dy, dy), 6.25f);
            const float t2 = __fmul_rn(__fmul_rn(dz, dz), 25.0f);
            const float qv = __fadd_rn(__fadd_rn(t0, t1), t2);
            const bool hit = qv < 1.0f;
            const unsigned long long m = __ballot(hit);
            if (first < 0 && m != 0ull) first = base + __builtin_ctzll(m);
            if (hit) {
                const int pos = cnt + __popcll(m & ((1ull << lane) - 1ull));
                if (pos < NS) idx_s[wave][pos] = i;
            }
            cnt += __popcll(m);
            if (cnt >= NS) break;
        }
        if (cnt < NS) {
            const int f = (cnt == 0) ? 0 : first;
            if (lane < NS && lane >= cnt) idx_s[wave][lane] = f;
        }
    }
    __syncthreads();

    const int s = tid & 31;
    const int h = (tid >> 5) & 1;
    const int q = tid >> 6;
    const int p = p0 + q;
    const int j = idx_s[q][s];
    float* ob = out + ((size_t)b * NCH * NQ + p) * NS + s;

    if (h == 0) {
        const float qx = nxyz[((size_t)b * NQ + p) * 3 + 0];
        const float qy = nxyz[((size_t)b * NQ + p) * 3 + 1];
        const float qz = nxyz[((size_t)b * NQ + p) * 3 + 2];
        const float px = xb[j * 3 + 0], py = xb[j * 3 + 1], pz = xb[j * 3 + 2];
        const float dx = __fsub_rn(px, qx);
        const float dy = __fsub_rn(py, qy);
        const float dz = __fsub_rn(pz, qz);
        const float d2 = __fadd_rn(__fadd_rn(__fmul_rn(dx, dx), __fmul_rn(dy, dy)),
                                   __fmul_rn(dz, dz));
        const float dist = __fsqrt_rn(d2);
        const float arg  = __fdiv_rn(-__fmul_rn(dist, dist), 0.02f);
        const float gd = __fdiv_rn(1.0f, __fmul_rn(expf(arg), 4.0f));
        ob[0 * (size_t)CS] = px;
        ob[1 * (size_t)CS] = py;
        ob[2 * (size_t)CS] = pz;
        ob[3 * (size_t)CS] = gd;
    }
    const float* fb = feat + (size_t)b * NC * NPTS + j;
    #pragma unroll 4
    for (int c = h; c < NC; c += 2)
        ob[(size_t)(4 + c) * CS] = fb[(size_t)c * NPTS];
}

extern "C" void kernel_launch(void* const* d_in, const int* in_sizes, int n_in,
                              void* d_out, int out_size, void* d_ws, size_t ws_size,
                              hipStream_t stream) {
    const float* xyz  = (const float*)d_in[0];   // (B, 8192, 3)
    const float* nxyz = (const float*)d_in[1];   // (B, 2048, 3)
    const float* feat = (const float*)d_in[2];   // (B, 64, 8192)
    float* out = (float*)d_out;                  // (B, 68, 2048, 32)

    const int B = in_sizes[0] / (NPTS * 3);
    const size_t ftr_f = (size_t)B * NPTS * NC;
    const size_t idx_f = (size_t)B * NQ * NS;
    const size_t need  = (ftr_f + idx_f) * 4;

    if (ws_size >= need) {
        float* ftr = (float*)d_ws;
        int*   idx = (int*)(ftr + ftr_f);

        const int ntrans = B * (NPTS / 64);      // 512 transpose blocks (first)
        const int nscan  = B * (NQ / 4);         // 2048 scan blocks
        scan_trans_kernel<<<dim3(ntrans + nscan), 256, 0, stream>>>(
            xyz, nxyz, feat, ftr, idx, out, ntrans);
        group_kernel<<<dim3(B * NQ), 512, 0, stream>>>(idx, ftr, out, B);
    } else {
        ellip_direct_kernel<<<dim3(NQ / 8, B), 512, 0, stream>>>(xyz, nxyz, feat, out);
    }
}

// Round 9
// 100.818 us; speedup vs baseline: 1.1173x; 1.1173x over previous
//
#include <hip/hip_runtime.h>

// Problem constants (from reference setup_inputs)
constexpr int NPTS = 8192;   // points per batch
constexpr int NQ   = 2048;   // query points per batch
constexpr int NC   = 64;     // feature channels
constexpr int NS   = 32;     // nsample
constexpr int NCH  = 3 + 1 + NC;           // 68 output channels
constexpr int CS   = NQ * NS;              // channel stride in output (floats)
constexpr int LPTS = 5120;   // points staged in LDS (60 KB; covers edge queries)
constexpr int QPB2 = 16;     // queries per scan block (16 waves, 1024 thr)

// Workspace layout (floats):  ftr : B*NPTS*NC  |  idx : B*NQ*NS (int32)

// R9 = R7 structure (best measured: LDS-staged scan + fused transpose,
// 2 graph nodes) with two fixes from the R8 post-mortem:
//  (1) LPTS 4096->5120: edge queries (~3800 pts to 32 hits) now finish in
//      phase A; the slow AoS-global phase B is corner-only (~few %).
//  (2) phase A processes 128 pts/iter (ds_read2_b32 pairs, dual ballot with
//      order-correct prefix) -> half the loop iterations.
// Measured context: group at write floor (13.4 us incl gap, R5); SoA/LDS
// beats AoS global scan by ~6-10 us (R8); harness fills ~66 us are fixed.

struct ScanLds { float pts[3][LPTS]; int idx[QPB2][NS]; };   // 63488 B < 64 KB
union  KLds    { ScanLds s; float tile[2][NC][65]; };

__device__ __forceinline__ unsigned prefix_popc(unsigned long long m) {
    // popcount of m restricted to lanes below this one (v_mbcnt pair)
    return __builtin_amdgcn_mbcnt_hi((unsigned)(m >> 32),
           __builtin_amdgcn_mbcnt_lo((unsigned)m, 0u));
}

__global__ __launch_bounds__(1024, 8) void scan_trans_kernel(
    const float* __restrict__ xyz,    // (B, NPTS, 3)
    const float* __restrict__ nxyz,   // (B, NQ, 3)
    const float* __restrict__ feat,   // (B, NC, NPTS)
    float* __restrict__ ftr,          // (B, NPTS, NC)
    int* __restrict__ gidx,           // (B, NQ, NS)
    float* __restrict__ out,          // (B, NCH, NQ, NS)
    int ntrans)
{
    __shared__ KLds u;
    const int bx = blockIdx.x;
    const int t  = threadIdx.x;

    if (bx < ntrans) {
        // ---- feature transpose: 2 tiles of 64 points, 512 thr each ----
        const int b   = bx >> 6;              // 64 t-blocks per batch
        const int tl2 = bx & 63;
        const int h   = t >> 9;               // tile half 0/1
        const int v   = t & 511;
        const int pl  = v & 63;               // lane within 64-pt tile
        const int c0  = v >> 6;               // 0..7 (wave-uniform)
        const int n0  = tl2 * 128 + h * 64;
        const float* fb = feat + (size_t)b * NC * NPTS;
        #pragma unroll
        for (int i = 0; i < 8; ++i) {         // loads coalesced 256B/row
            const int c = c0 + 8 * i;
            u.tile[h][c][pl] = fb[(size_t)c * NPTS + n0 + pl];  // bank lane%32: free
        }
        __syncthreads();
        float* tb = ftr + ((size_t)b * NPTS + n0) * NC;
        #pragma unroll
        for (int i = 0; i < 8; ++i) {         // stores coalesced 256B/point
            const int pp = c0 + 8 * i;
            tb[(size_t)pp * NC + pl] = u.tile[h][pl][pp];       // (pl*65+pp)%32: free
        }
        return;
    }

    // ---- scan block: 16 queries, LDS-staged first-5120 points ----
    const int sb   = bx - ntrans;
    const int qpb  = NQ / QPB2;               // 128 scan-blocks per batch
    const int b    = sb / qpb;
    const int p0   = (sb - b * qpb) * QPB2;
    const int lane = t & 63;
    const int wave = t >> 6;                  // 0..15
    const float* xb = xyz + (size_t)b * NPTS * 3;

    // stage pts[3][LPTS]: 15360 dwords, 15/thread, coalesced reads
    #pragma unroll
    for (int k = 0; k < 3 * LPTS / 1024; ++k) {
        const int g  = k * 1024 + t;
        const float val = xb[g];
        const int pt = g / 3;                 // magic-mul
        const int c  = g - 3 * pt;
        u.s.pts[c][pt] = val;
    }
    __syncthreads();

    const int p = p0 + wave;
    const float qx = nxyz[((size_t)b * NQ + p) * 3 + 0];
    const float qy = nxyz[((size_t)b * NQ + p) * 3 + 1];
    const float qz = nxyz[((size_t)b * NQ + p) * 3 + 2];

    int cnt = 0;      // wave-uniform hit count
    int first = -1;   // wave-uniform first-hit index
    int* idx_row = u.s.idx[wave];

    // phase A: LDS, 128 points per iteration (two 64-pt chunks).
    // Strict per-op rounding in the reference's evaluation order: q<1.0 is
    // discontinuous -> no FMA contraction allowed in the test.
    for (int base = 0; base < LPTS; base += 128) {
        const int i0 = base + lane;
        const int i1 = i0 + 64;
        const float xA = u.s.pts[0][i0];      // pairs fuse to ds_read2_b32;
        const float xB = u.s.pts[0][i1];      // stride-1 lanes: 2-way, free
        const float yA = u.s.pts[1][i0];
        const float yB = u.s.pts[1][i1];
        const float zA = u.s.pts[2][i0];
        const float zB = u.s.pts[2][i1];

        const float dxA = __fsub_rn(qx, xA);
        const float dyA = __fsub_rn(qy, yA);
        const float dzA = __fsub_rn(qz, zA);
        const float qA  = __fadd_rn(__fadd_rn(
                            __fmul_rn(__fmul_rn(dxA, dxA), 25.0f),
                            __fmul_rn(__fmul_rn(dyA, dyA), 6.25f)),
                            __fmul_rn(__fmul_rn(dzA, dzA), 25.0f));
        const float dxB = __fsub_rn(qx, xB);
        const float dyB = __fsub_rn(qy, yB);
        const float dzB = __fsub_rn(qz, zB);
        const float qB  = __fadd_rn(__fadd_rn(
                            __fmul_rn(__fmul_rn(dxB, dxB), 25.0f),
                            __fmul_rn(__fmul_rn(dyB, dyB), 6.25f)),
                            __fmul_rn(__fmul_rn(dzB, dzB), 25.0f));
        const bool hitA = qA < 1.0f;
        const bool hitB = qB < 1.0f;

        const unsigned long long m0 = __ballot(hitA);
        const unsigned long long m1 = __ballot(hitB);
        if (first < 0) {                      // wave-uniform
            if (m0 != 0ull)      first = base + __builtin_ctzll(m0);
            else if (m1 != 0ull) first = base + 64 + __builtin_ctzll(m1);
        }
        if (hitA) {
            const int pos = cnt + (int)prefix_popc(m0);
            if (pos < NS) idx_row[pos] = i0;
        }
        const int c0 = __popcll(m0);
        if (hitB) {
            const int pos = cnt + c0 + (int)prefix_popc(m1);
            if (pos < NS) idx_row[pos] = i1;
        }
        cnt += c0 + __popcll(m1);
        if (cnt >= NS) break;                 // uniform early exit
    }

    // phase B (corner queries only): global AoS tail with prefetch-2
    if (cnt < NS) {
        float x0 = xb[3 * (LPTS + lane) + 0];
        float y0 = xb[3 * (LPTS + lane) + 1];
        float z0 = xb[3 * (LPTS + lane) + 2];
        float x1 = xb[3 * (LPTS + 64 + lane) + 0];
        float y1 = xb[3 * (LPTS + 64 + lane) + 1];
        float z1 = xb[3 * (LPTS + 64 + lane) + 2];
        for (int base = LPTS; base < NPTS; base += 64) {
            float xn = 0.f, yn = 0.f, zn = 0.f;
            const int pf = base + 128;
            if (pf < NPTS) {                  // wave-uniform guard
                xn = xb[3 * (pf + lane) + 0];
                yn = xb[3 * (pf + lane) + 1];
                zn = xb[3 * (pf + lane) + 2];
            }
            const float dx = __fsub_rn(qx, x0);
            const float dy = __fsub_rn(qy, y0);
            const float dz = __fsub_rn(qz, z0);
            const float t0 = __fmul_rn(__fmul_rn(dx, dx), 25.0f);
            const float t1 = __fmul_rn(__fmul_rn(dy, dy), 6.25f);
            const float t2 = __fmul_rn(__fmul_rn(dz, dz), 25.0f);
            const float qv = __fadd_rn(__fadd_rn(t0, t1), t2);
            const bool hit = qv < 1.0f;

            const unsigned long long m = __ballot(hit);
            if (first < 0 && m != 0ull)
                first = base + __builtin_ctzll(m);
            if (hit) {
                const int pos = cnt + (int)prefix_popc(m);
                if (pos < NS) idx_row[pos] = base + lane;
            }
            cnt += __popcll(m);
            if (cnt >= NS) break;
            x0 = x1; y0 = y1; z0 = z1;
            x1 = xn; y1 = yn; z1 = zn;
        }
    }

    if (cnt < NS) {
        const int f = (cnt == 0) ? 0 : first;        // pad (0 if empty)
        if (lane < NS && lane >= cnt) idx_row[lane] = f;
    }

    // epilogue: lanes 0..31 emit idx + channels 0..3
    if (lane < NS) {
        const int s = lane;
        const int j = idx_row[s];                    // same-wave LDS RAW: safe
        gidx[((size_t)b * NQ + p) * NS + s] = j;

        const float px = xb[3 * j + 0];
        const float py = xb[3 * j + 1];
        const float pz = xb[3 * j + 2];
        const float dx = __fsub_rn(px, qx);
        const float dy = __fsub_rn(py, qy);
        const float dz = __fsub_rn(pz, qz);
        const float d2 = __fadd_rn(__fadd_rn(__fmul_rn(dx, dx), __fmul_rn(dy, dy)),
                                   __fmul_rn(dz, dz));
        const float dist = __fsqrt_rn(d2);
        const float arg  = __fdiv_rn(-__fmul_rn(dist, dist), 0.02f);
        const float density = __fmul_rn(expf(arg), 4.0f);  // /0.25 == *4 exact
        const float gd = __fdiv_rn(1.0f, density);         // inf on underflow == ref

        float* ob = out + ((size_t)b * NCH * NQ + p) * NS + s;
        ob[0 * (size_t)CS] = px;
        ob[1 * (size_t)CS] = py;
        ob[2 * (size_t)CS] = pz;
        ob[3 * (size_t)CS] = gd;
    }
}

// ---------------------------------------------------------------------------
// K2: feature grouping (R4 version, measured at write-BW floor ~11-13 us).
// ---------------------------------------------------------------------------
__global__ __launch_bounds__(512, 8) void group_kernel(
    const int* __restrict__ gidx,     // (B, NQ, NS)
    const float* __restrict__ ftr,    // (B, NPTS, NC)
    float* __restrict__ out,          // (B, NCH, NQ, NS)
    int B)
{
    __shared__ float ldsc[NC][33];

    const int g = blockIdx.x;
    int b, p;
    if (B == 4) {
        b = (g & 7) >> 1;                     // XCD-pair -> batch
        p = ((g >> 3) << 1) | (g & 1);
    } else {
        b = g / NQ;
        p = g - b * NQ;
    }
    const int tid = threadIdx.x;

    // ---- gather phase: lane = (sl, cg) ----
    const int cg = tid & 15;                  // channel group 0..15 (float4)
    const int sl = tid >> 4;                  // sample 0..31
    const int j  = gidx[((size_t)b * NQ + p) * NS + sl];
    const float4 v = ((const float4*)(ftr + ((size_t)b * NPTS + j) * NC))[cg];
    ldsc[4 * cg + 0][sl] = v.x;               // bank (4cg+i+sl)%32 -> 2-way, free
    ldsc[4 * cg + 1][sl] = v.y;
    ldsc[4 * cg + 2][sl] = v.z;
    ldsc[4 * cg + 3][sl] = v.w;
    __syncthreads();

    // ---- store phase: lane = (c, s4) ----
    const int c  = tid >> 3;                  // channel 0..63
    const int s4 = (tid & 7) << 2;            // sample base 0,4,...,28
    float4 w;
    w.x = ldsc[c][s4 + 0];                    // bank (c+s4+i)%32 -> <=2-way, free
    w.y = ldsc[c][s4 + 1];
    w.z = ldsc[c][s4 + 2];
    w.w = ldsc[c][s4 + 3];
    float* op = out + (((size_t)b * NCH + 4 + c) * NQ + p) * NS + s4;
    *(float4*)op = w;                         // 8 x 128B segments per wave store
}

// ---------------------------------------------------------------------------
// Fallback (tiny ws): R1-style fused direct kernel.
// ---------------------------------------------------------------------------
__global__ __launch_bounds__(512, 8) void ellip_direct_kernel(
    const float* __restrict__ xyz,
    const float* __restrict__ nxyz,
    const float* __restrict__ feat,
    float* __restrict__ out)
{
    __shared__ int idx_s[8][NS];

    const int b    = blockIdx.y;
    const int p0   = blockIdx.x * 8;
    const int tid  = threadIdx.x;
    const int lane = tid & 63;
    const int wave = tid >> 6;
    const float* xb = xyz + (size_t)b * NPTS * 3;

    {
        const int p = p0 + wave;
        const float qx = nxyz[((size_t)b * NQ + p) * 3 + 0];
        const float qy = nxyz[((size_t)b * NQ + p) * 3 + 1];
        const float qz = nxyz[((size_t)b * NQ + p) * 3 + 2];
        int cnt = 0, first = -1;
        for (int base = 0; base < NPTS; base += 64) {
            const int i = base + lane;
            const float dx = __fsub_rn(qx, xb[i * 3 + 0]);
            const float dy = __fsub_rn(qy, xb[i * 3 + 1]);
            const float dz = __fsub_rn(qz, xb[i * 3 + 2]);
            const float t0 = __fmul_rn(__fmul_rn(dx, dx), 25.0f);
            const float t1 = __fmul_rn(__fmul_rn(dy, dy), 6.25f);
            const float t2 = __fmul_rn(__fmul_rn(dz, dz), 25.0f);
            const float qv = __fadd_rn(__fadd_rn(t0, t1), t2);
            const bool hit = qv < 1.0f;
            const unsigned long long m = __ballot(hit);
            if (first < 0 && m != 0ull) first = base + __builtin_ctzll(m);
            if (hit) {
                const int pos = cnt + __popcll(m & ((1ull << lane) - 1ull));
                if (pos < NS) idx_s[wave][pos] = i;
            }
            cnt += __popcll(m);
            if (cnt >= NS) break;
        }
        if (cnt < NS) {
            const int f = (cnt == 0) ? 0 : first;
            if (lane < NS && lane >= cnt) idx_s[wave][lane] = f;
        }
    }
    __syncthreads();

    const int s = tid & 31;
    const int h = (tid >> 5) & 1;
    const int q = tid >> 6;
    const int p = p0 + q;
    const int j = idx_s[q][s];
    float* ob = out + ((size_t)b * NCH * NQ + p) * NS + s;

    if (h == 0) {
        const float qx = nxyz[((size_t)b * NQ + p) * 3 + 0];
        const float qy = nxyz[((size_t)b * NQ + p) * 3 + 1];
        const float qz = nxyz[((size_t)b * NQ + p) * 3 + 2];
        const float px = xb[j * 3 + 0], py = xb[j * 3 + 1], pz = xb[j * 3 + 2];
        const float dx = __fsub_rn(px, qx);
        const float dy = __fsub_rn(py, qy);
        const float dz = __fsub_rn(pz, qz);
        const float d2 = __fadd_rn(__fadd_rn(__fmul_rn(dx, dx), __fmul_rn(dy, dy)),
                                   __fmul_rn(dz, dz));
        const float dist = __fsqrt_rn(d2);
        const float arg  = __fdiv_rn(-__fmul_rn(dist, dist), 0.02f);
        const float gd = __fdiv_rn(1.0f, __fmul_rn(expf(arg), 4.0f));
        ob[0 * (size_t)CS] = px;
        ob[1 * (size_t)CS] = py;
        ob[2 * (size_t)CS] = pz;
        ob[3 * (size_t)CS] = gd;
    }
    const float* fb = feat + (size_t)b * NC * NPTS + j;
    #pragma unroll 4
    for (int c = h; c < NC; c += 2)
        ob[(size_t)(4 + c) * CS] = fb[(size_t)c * NPTS];
}

extern "C" void kernel_launch(void* const* d_in, const int* in_sizes, int n_in,
                              void* d_out, int out_size, void* d_ws, size_t ws_size,
                              hipStream_t stream) {
    const float* xyz  = (const float*)d_in[0];   // (B, 8192, 3)
    const float* nxyz = (const float*)d_in[1];   // (B, 2048, 3)
    const float* feat = (const float*)d_in[2];   // (B, 64, 8192)
    float* out = (float*)d_out;                  // (B, 68, 2048, 32)

    const int B = in_sizes[0] / (NPTS * 3);
    const size_t ftr_f = (size_t)B * NPTS * NC;
    const size_t idx_f = (size_t)B * NQ * NS;
    const size_t need  = (ftr_f + idx_f) * 4;

    if (ws_size >= need) {
        float* ftr = (float*)d_ws;
        int*   idx = (int*)(ftr + ftr_f);

        const int ntrans = B * 64;               // transpose blocks (first)
        const int nscan  = B * (NQ / QPB2);      // scan blocks
        scan_trans_kernel<<<dim3(ntrans + nscan), 1024, 0, stream>>>(
            xyz, nxyz, feat, ftr, idx, out, ntrans);
        group_kernel<<<dim3(B * NQ), 512, 0, stream>>>(idx, ftr, out, B);
    } else {
        ellip_direct_kernel<<<dim3(NQ / 8, B), 512, 0, stream>>>(xyz, nxyz, feat, out);
    }
}